// Round 7
// baseline (79.953 us; speedup 1.0000x reference)
//
#include <hip/hip_runtime.h>

// Problem constants (from reference)
constexpr int N = 2;
constexpr int C = 20;
constexpr int H = 64;
constexpr int W = 2048;          // power of two -> wrap via & (W-1)
constexpr int HW = H * W;

constexpr int BLK   = 256;       // 128 site-pair threads x 2 class-halves
constexpr int SITES = 256;       // sites per block (128 pairs)
// grid = N*H*(W/SITES) = 2*64*8 = 1024 blocks -> 4096 waves -> 16 waves/CU

__global__ __launch_bounds__(BLK, 4)   // force VGPR<=128 -> 4 blocks/CU resident
void lcl_xyz_kernel(const float* __restrict__ xyz,
                    const float* __restrict__ softmax,
                    const int* __restrict__ mask,
                    float* __restrict__ out) {
    const int t  = threadIdx.x;
    const int sp = t & 127;                 // site-pair index
    const int ch = t >> 7;                  // class half: 0 -> 0..9, 1 -> 10..19

    // XCD-contiguous strip swizzle: XCD (bid%8) owns 128 consecutive work ids
    // -> 16 contiguous (n*64+h) rows per XCD L2.
    const int bid  = blockIdx.x;
    const int work = (bid & 7) * 128 + (bid >> 3);   // bijective over [0,1024)
    const int nh   = work >> 3;
    const int bw   = work & 7;
    const int n    = nh >> 6;
    const int h    = nh & 63;
    const int w    = bw * SITES + 2 * sp;   // even; first of this thread's 2 sites

    // Clipped row offsets + validity
    int  rowoff[5];
    bool hv[5];
    #pragma unroll
    for (int r = 0; r < 5; ++r) {
        int hh = h - 2 + r;
        hv[r] = (unsigned)hh < (unsigned)H;
        rowoff[r] = min(max(hh, 0), H - 1) * W;
    }

    // Aligned float2 column offsets covering cols w-2 .. w+3
    const int cm = (w - 2) & (W - 1);
    const int c0 = w;
    const int cp = (w + 2) & (W - 1);

    const float* xb = xyz + (size_t)(n * 3 + 0) * HW;
    const float* yb = xyz + (size_t)(n * 3 + 1) * HW;
    const float* zb = xyz + (size_t)(n * 3 + 2) * HW;
    const int*   mb = mask + (size_t)n * HW;

    const float2 cx2 = *(const float2*)(xb + h * W + c0);
    const float2 cy2 = *(const float2*)(yb + h * W + c0);
    const float2 cz2 = *(const float2*)(zb + h * W + c0);

    // ---- Weight phase: 50 gaussian*mask*valid weights in registers ----
    // (duplicated across the two class-halves; ~25% of instructions, overlapped)
    float wa[5][5], wb_[5][5];
    #pragma unroll
    for (int r = 0; r < 5; ++r) {
        float2 xm = *(const float2*)(xb + rowoff[r] + cm);
        float2 x0 = *(const float2*)(xb + rowoff[r] + c0);
        float2 xp = *(const float2*)(xb + rowoff[r] + cp);
        float2 ym = *(const float2*)(yb + rowoff[r] + cm);
        float2 y0 = *(const float2*)(yb + rowoff[r] + c0);
        float2 yp = *(const float2*)(yb + rowoff[r] + cp);
        float2 zm = *(const float2*)(zb + rowoff[r] + cm);
        float2 z0 = *(const float2*)(zb + rowoff[r] + c0);
        float2 zp = *(const float2*)(zb + rowoff[r] + cp);
        int2   km = *(const int2*)(mb + rowoff[r] + cm);
        int2   k0 = *(const int2*)(mb + rowoff[r] + c0);
        int2   kp = *(const int2*)(mb + rowoff[r] + cp);

        const float xv[6] = {xm.x, xm.y, x0.x, x0.y, xp.x, xp.y};
        const float yv[6] = {ym.x, ym.y, y0.x, y0.y, yp.x, yp.y};
        const float zv[6] = {zm.x, zm.y, z0.x, z0.y, zp.x, zp.y};
        const int   mv[6] = {km.x, km.y, k0.x, k0.y, kp.x, kp.y};

        #pragma unroll
        for (int j = 0; j < 5; ++j) {
            {
                float dx = xv[j] - cx2.x, dy = yv[j] - cy2.x, dz = zv[j] - cz2.x;
                float g  = __expf(-0.5f * (dx * dx + dy * dy + dz * dz));
                wa[r][j] = (hv[r] && mv[j]) ? g : 0.0f;
            }
            {
                float dx = xv[j + 1] - cx2.y, dy = yv[j + 1] - cy2.y, dz = zv[j + 1] - cz2.y;
                float g  = __expf(-0.5f * (dx * dx + dy * dy + dz * dz));
                wb_[r][j] = (hv[r] && mv[j + 1]) ? g : 0.0f;
            }
        }
    }

    // ---- Class loop: this thread's 10 classes, 15 float2 loads + 50 FMA each ----
    const float* smb = softmax + (size_t)n * C * HW;
    float*       ob  = out + (size_t)n * C * HW + (size_t)h * W + w;
    const int    cb  = ch * 10;

    #pragma unroll 2
    for (int c = cb; c < cb + 10; ++c) {
        const float* sc = smb + (size_t)c * HW;
        float2 b0[5], b1[5], b2[5];
        #pragma unroll
        for (int r = 0; r < 5; ++r) {
            b0[r] = *(const float2*)(sc + rowoff[r] + cm);
            b1[r] = *(const float2*)(sc + rowoff[r] + c0);
            b2[r] = *(const float2*)(sc + rowoff[r] + cp);
        }
        float a0 = 0.0f, a1 = 0.0f;
        #pragma unroll
        for (int r = 0; r < 5; ++r) {
            float v0 = b0[r].x, v1 = b0[r].y;
            float v2 = b1[r].x, v3 = b1[r].y;
            float v4 = b2[r].x, v5 = b2[r].y;
            a0 = fmaf(wa[r][0], v0, a0);
            a0 = fmaf(wa[r][1], v1, a0);
            a0 = fmaf(wa[r][2], v2, a0);
            a0 = fmaf(wa[r][3], v3, a0);
            a0 = fmaf(wa[r][4], v4, a0);
            a1 = fmaf(wb_[r][0], v1, a1);
            a1 = fmaf(wb_[r][1], v2, a1);
            a1 = fmaf(wb_[r][2], v3, a1);
            a1 = fmaf(wb_[r][3], v4, a1);
            a1 = fmaf(wb_[r][4], v5, a1);
        }
        float2 o; o.x = a0; o.y = a1;
        *(float2*)(ob + (size_t)c * HW) = o;
    }
}

extern "C" void kernel_launch(void* const* d_in, const int* in_sizes, int n_in,
                              void* d_out, int out_size, void* d_ws, size_t ws_size,
                              hipStream_t stream) {
    const float* xyz     = (const float*)d_in[0];
    const float* softmax = (const float*)d_in[1];
    const int*   mask    = (const int*)d_in[2];
    float*       out     = (float*)d_out;

    const int grid = N * H * (W / SITES);     // 1024 blocks
    lcl_xyz_kernel<<<grid, BLK, 0, stream>>>(xyz, softmax, mask, out);
}

// Round 8
// 25.380 us; speedup vs baseline: 3.1502x; 3.1502x over previous
//
#include <hip/hip_runtime.h>

// Problem constants (from reference)
constexpr int N = 2;
constexpr int C = 20;
constexpr int H = 64;
constexpr int W = 2048;          // power of two -> wrap via & (W-1)
constexpr int HW = H * W;

constexpr int BLK   = 256;
constexpr int TILE  = 512;           // outputs per block along w (2 per thread)
constexpr int LCOLS = 520;           // staged cols: w0-4 .. w0+515 (covers w0+513)
constexpr int F4    = LCOLS / 4;     // 130 float4 items per row
constexpr int ITEMS = 5 * F4;        // 650 real items per slab
constexpr int PITEM = 768;           // padded items -> uniform 3 loads/thread
// grid = N*H*(W/TILE) = 2*64*4 = 512 blocks -> 8 waves/CU, 2 blocks/CU

#define GLDS16(g, l)                                                        \
    __builtin_amdgcn_global_load_lds(                                       \
        (const __attribute__((address_space(1))) void*)(g),                 \
        (__attribute__((address_space(3))) void*)(l), 16, 0, 0)

__global__ __launch_bounds__(BLK, 2)
void lcl_xyz_kernel(const float* __restrict__ xyz,
                    const float* __restrict__ softmax,
                    const int* __restrict__ mask,
                    float* __restrict__ out) {
    // Overlaid LDS: phase 1 = {sx,sy,sz,sk} (10400 floats), phase 2 = 3 softmax
    // slabs of 3072 floats each (9216). Single 41.6 KB region.
    __shared__ __align__(16) float lds[10400];
    float* sx = lds;                 // 2600 floats (5 rows x 520)
    float* sy = lds + 2600;
    float* sz = lds + 5200;
    int*   sk = (int*)(lds + 7800);  // 2600 ints
    float* sp0 = lds;                // 3072 floats (650 items + pad)
    float* sp1 = lds + 3072;
    float* sp2 = lds + 6144;

    const int t = threadIdx.x;

    // XCD-contiguous strip swizzle (XCD = bid%8 round-robin assumption):
    // XCD k owns 64 consecutive work ids = 16 contiguous (n*64+h) rows.
    const int bid  = blockIdx.x;
    const int work = (bid & 7) * 64 + (bid >> 3);   // bijective over [0,512)
    const int nh   = work >> 2;
    const int bw   = work & 3;
    const int n    = nh >> 6;
    const int h    = nh & 63;
    const int w0   = bw * TILE;

    int  rowoff[5];
    bool hv[5];
    #pragma unroll
    for (int r = 0; r < 5; ++r) {
        int hh = h - 2 + r;
        hv[r] = (unsigned)hh < (unsigned)H;
        rowoff[r] = min(max(hh, 0), H - 1) * W;
    }

    const float* xb  = xyz + (size_t)(n * 3 + 0) * HW;
    const float* yb  = xyz + (size_t)(n * 3 + 1) * HW;
    const float* zb  = xyz + (size_t)(n * 3 + 2) * HW;
    const int*   mb  = mask + (size_t)n * HW;
    const float* smb = softmax + (size_t)n * C * HW;

    // Class-independent staging tuples (3 uniform loads/thread/slab).
    // Items 650..767 re-load item (it-650) into the pad region (benign).
    int src_off0, src_off1, src_off2;
    const int ldo0 = t * 16, ldo1 = (t + 256) * 16, ldo2 = (t + 512) * 16;
    {
        int its[3];
        its[0] = t; its[1] = t + 256;
        its[2] = (t + 512 < ITEMS) ? t + 512 : t + 512 - ITEMS;
        int so[3];
        #pragma unroll
        for (int i = 0; i < 3; ++i) {
            int r = its[i] / F4;
            int k = its[i] - r * F4;
            so[i] = rowoff[r] + ((w0 - 4 + 4 * k) & (W - 1));
        }
        src_off0 = so[0]; src_off1 = so[1]; src_off2 = so[2];
    }

    // ---- Stage xyz + mask (guarded 3rd iter; drained by syncthreads) ----
    GLDS16(xb + src_off0, (char*)sx + ldo0);
    GLDS16(yb + src_off0, (char*)sy + ldo0);
    GLDS16(zb + src_off0, (char*)sz + ldo0);
    GLDS16(mb + src_off0, (char*)sk + ldo0);
    GLDS16(xb + src_off1, (char*)sx + ldo1);
    GLDS16(yb + src_off1, (char*)sy + ldo1);
    GLDS16(zb + src_off1, (char*)sz + ldo1);
    GLDS16(mb + src_off1, (char*)sk + ldo1);
    if (t + 512 < ITEMS) {
        GLDS16(xb + src_off2, (char*)sx + ldo2);
        GLDS16(yb + src_off2, (char*)sy + ldo2);
        GLDS16(zb + src_off2, (char*)sz + ldo2);
        GLDS16(mb + src_off2, (char*)sk + ldo2);
    }
    __syncthreads();

    // ---- Masked dist2 (then exp in place). base = local col of leftmost tap.
    const int base = 2 * t + 2;
    float wa[5][5], wb_[5][5];
    {
        const float2 cx2 = *(const float2*)(sx + 2 * 520 + base + 2);
        const float2 cy2 = *(const float2*)(sy + 2 * 520 + base + 2);
        const float2 cz2 = *(const float2*)(sz + 2 * 520 + base + 2);
        #pragma unroll
        for (int r = 0; r < 5; ++r) {
            const float* px = sx + r * 520 + base;
            const float* py = sy + r * 520 + base;
            const float* pz = sz + r * 520 + base;
            const int*   pm = sk + r * 520 + base;
            float2 x0 = *(const float2*)(px),  x1 = *(const float2*)(px + 2), x2 = *(const float2*)(px + 4);
            float2 y0 = *(const float2*)(py),  y1 = *(const float2*)(py + 2), y2 = *(const float2*)(py + 4);
            float2 z0 = *(const float2*)(pz),  z1 = *(const float2*)(pz + 2), z2 = *(const float2*)(pz + 4);
            int2   m0 = *(const int2*)(pm),    m1 = *(const int2*)(pm + 2),   m2 = *(const int2*)(pm + 4);
            const float xv[6] = {x0.x, x0.y, x1.x, x1.y, x2.x, x2.y};
            const float yv[6] = {y0.x, y0.y, y1.x, y1.y, y2.x, y2.y};
            const float zv[6] = {z0.x, z0.y, z1.x, z1.y, z2.x, z2.y};
            const int   mv[6] = {m0.x, m0.y, m1.x, m1.y, m2.x, m2.y};
            #pragma unroll
            for (int j = 0; j < 5; ++j) {
                float dx = xv[j] - cx2.x, dy = yv[j] - cy2.x, dz = zv[j] - cz2.x;
                float d2 = dx * dx + dy * dy + dz * dz;
                wa[r][j] = (hv[r] && mv[j]) ? d2 : 1e30f;     // masked -> exp->0
                float ex = xv[j + 1] - cx2.y, ey = yv[j + 1] - cy2.y, ez = zv[j + 1] - cz2.y;
                float e2 = ex * ex + ey * ey + ez * ez;
                wb_[r][j] = (hv[r] && mv[j + 1]) ? e2 : 1e30f;
            }
        }
    }
    __syncthreads();    // xyz/mask region now dead -> safe to overlay

    // ---- Prime pipeline: class 0 -> sp0, class 1 -> sp1 (async) ----
    {
        const float* s0 = smb;
        GLDS16(s0 + src_off0, (char*)sp0 + ldo0);
        GLDS16(s0 + src_off1, (char*)sp0 + ldo1);
        GLDS16(s0 + src_off2, (char*)sp0 + ldo2);
        const float* s1 = smb + (size_t)HW;
        GLDS16(s1 + src_off0, (char*)sp1 + ldo0);
        GLDS16(s1 + src_off1, (char*)sp1 + ldo1);
        GLDS16(s1 + src_off2, (char*)sp1 + ldo2);
    }

    // exp math overlaps the in-flight staging
    #pragma unroll
    for (int r = 0; r < 5; ++r)
        #pragma unroll
        for (int j = 0; j < 5; ++j) {
            wa[r][j]  = __expf(-0.5f * wa[r][j]);
            wb_[r][j] = __expf(-0.5f * wb_[r][j]);
        }

    float2 acc[C];

    // One step: counted wait (only staging loads in the vmcnt stream),
    // raw barrier, issue class CLS+2, compute class CLS from its slab.
#define STEP(CLS, PCUR, PNXT, KLIT)                                          \
    do {                                                                     \
        asm volatile("s_waitcnt vmcnt(" #KLIT ")\n\ts_barrier" ::: "memory");\
        if ((CLS) + 2 < C) {                                                 \
            const float* scn = smb + (size_t)((CLS) + 2) * HW;               \
            GLDS16(scn + src_off0, (char*)(PNXT) + ldo0);                    \
            GLDS16(scn + src_off1, (char*)(PNXT) + ldo1);                    \
            GLDS16(scn + src_off2, (char*)(PNXT) + ldo2);                    \
        }                                                                    \
        float a0 = 0.f, a1 = 0.f;                                            \
        _Pragma("unroll")                                                    \
        for (int r = 0; r < 5; ++r) {                                        \
            const float* rw = (PCUR) + r * 520 + base;                       \
            float2 u0 = *(const float2*)(rw);                                \
            float2 u1 = *(const float2*)(rw + 2);                            \
            float2 u2 = *(const float2*)(rw + 4);                            \
            a0 = fmaf(wa[r][0], u0.x, a0);  a0 = fmaf(wa[r][1], u0.y, a0);   \
            a0 = fmaf(wa[r][2], u1.x, a0);  a0 = fmaf(wa[r][3], u1.y, a0);   \
            a0 = fmaf(wa[r][4], u2.x, a0);                                   \
            a1 = fmaf(wb_[r][0], u0.y, a1); a1 = fmaf(wb_[r][1], u1.x, a1);  \
            a1 = fmaf(wb_[r][2], u1.y, a1); a1 = fmaf(wb_[r][3], u2.x, a1);  \
            a1 = fmaf(wb_[r][4], u2.y, a1);                                  \
        }                                                                    \
        acc[CLS].x = a0; acc[CLS].y = a1;                                    \
    } while (0)

    STEP( 0, sp0, sp2, 3);  STEP( 1, sp1, sp0, 3);  STEP( 2, sp2, sp1, 3);
    STEP( 3, sp0, sp2, 3);  STEP( 4, sp1, sp0, 3);  STEP( 5, sp2, sp1, 3);
    STEP( 6, sp0, sp2, 3);  STEP( 7, sp1, sp0, 3);  STEP( 8, sp2, sp1, 3);
    STEP( 9, sp0, sp2, 3);  STEP(10, sp1, sp0, 3);  STEP(11, sp2, sp1, 3);
    STEP(12, sp0, sp2, 3);  STEP(13, sp1, sp0, 3);  STEP(14, sp2, sp1, 3);
    STEP(15, sp0, sp2, 3);  STEP(16, sp1, sp0, 3);  STEP(17, sp2, sp1, 3);
    STEP(18, sp0, sp2, 3);  STEP(19, sp1, sp0, 0);
#undef STEP

    // ---- Epilogue: coalesced float2 stores, one per class ----
    float* ob = out + (size_t)n * C * HW + (size_t)h * W + w0 + 2 * t;
    #pragma unroll
    for (int c = 0; c < C; ++c)
        *(float2*)(ob + (size_t)c * HW) = acc[c];
}

extern "C" void kernel_launch(void* const* d_in, const int* in_sizes, int n_in,
                              void* d_out, int out_size, void* d_ws, size_t ws_size,
                              hipStream_t stream) {
    const float* xyz     = (const float*)d_in[0];
    const float* softmax = (const float*)d_in[1];
    const int*   mask    = (const int*)d_in[2];
    float*       out     = (float*)d_out;

    const int grid = N * H * (W / TILE);     // 512 blocks
    lcl_xyz_kernel<<<grid, BLK, 0, stream>>>(xyz, softmax, mask, out);
}

// Round 9
// 25.366 us; speedup vs baseline: 3.1519x; 1.0006x over previous
//
#include <hip/hip_runtime.h>

// Problem constants (from reference)
constexpr int N = 2;
constexpr int C = 20;
constexpr int H = 64;
constexpr int W = 2048;          // power of two -> wrap via & (W-1)
constexpr int HW = H * W;

constexpr int BLK  = 256;        // 4 waves; each wave owns a 128-col strip
constexpr int TILE = 512;        // outputs per block along w (2 per thread)
// Per-wave slab: 5 rows x 35 float4 (140 floats, cols W0-4 .. W0+135)
constexpr int RITEMS = 175;      // real float4 items per slab
constexpr int ROWF4  = 35;
constexpr int ROWF   = 140;      // floats per row
constexpr int SLABF  = 768;      // slab stride in floats (175*4=700, padded to 768 = 3072B)
// LDS: 4 waves x 4 slabs x 3072B = 48 KB. grid = 2*64*4 = 512 blocks = 2 blocks/CU.

#define GLDS16(g, l)                                                        \
    __builtin_amdgcn_global_load_lds(                                       \
        (const __attribute__((address_space(1))) void*)(g),                 \
        (__attribute__((address_space(3))) void*)(l), 16, 0, 0)

__global__ __launch_bounds__(BLK, 2)
void lcl_xyz_kernel(const float* __restrict__ xyz,
                    const float* __restrict__ softmax,
                    const int* __restrict__ mask,
                    float* __restrict__ out) {
    __shared__ __align__(16) float lds[4 * 4 * SLABF];   // 48 KB

    const int t  = threadIdx.x;
    const int l  = t & 63;                // lane
    const int wv = t >> 6;                // wave id 0..3

    // XCD-contiguous strip swizzle: XCD (bid%8) owns 64 consecutive work ids
    // = 16 contiguous (n*64+h) rows per XCD L2.
    const int bid  = blockIdx.x;
    const int work = (bid & 7) * 64 + (bid >> 3);   // bijective over [0,512)
    const int nh   = work >> 2;
    const int bw   = work & 3;
    const int n    = nh >> 6;
    const int h    = nh & 63;
    const int w0   = bw * TILE;
    const int w    = w0 + 2 * t;          // this thread's first output col
    const int W0   = w0 + 128 * wv;       // wave strip base col

    int  rowoff[5];
    bool hv[5];
    #pragma unroll
    for (int r = 0; r < 5; ++r) {
        int hh = h - 2 + r;
        hv[r] = (unsigned)hh < (unsigned)H;
        rowoff[r] = min(max(hh, 0), H - 1) * W;
    }

    const float* xb  = xyz + (size_t)(n * 3 + 0) * HW;
    const float* yb  = xyz + (size_t)(n * 3 + 1) * HW;
    const float* zb  = xyz + (size_t)(n * 3 + 2) * HW;
    const int*   mb  = mask + (size_t)n * HW;
    const float* smb = softmax + (size_t)n * C * HW;

    // ---- Weight phase: direct global float2 loads (one-time, no LDS, no sync) ----
    const int cm = (w - 2) & (W - 1);
    const int c0 = w;
    const int cp = (w + 2) & (W - 1);

    const float2 cx2 = *(const float2*)(xb + h * W + c0);
    const float2 cy2 = *(const float2*)(yb + h * W + c0);
    const float2 cz2 = *(const float2*)(zb + h * W + c0);

    float wa[5][5], wb_[5][5];
    #pragma unroll
    for (int r = 0; r < 5; ++r) {
        float2 xm = *(const float2*)(xb + rowoff[r] + cm);
        float2 x0 = *(const float2*)(xb + rowoff[r] + c0);
        float2 xp = *(const float2*)(xb + rowoff[r] + cp);
        float2 ym = *(const float2*)(yb + rowoff[r] + cm);
        float2 y0 = *(const float2*)(yb + rowoff[r] + c0);
        float2 yp = *(const float2*)(yb + rowoff[r] + cp);
        float2 zm = *(const float2*)(zb + rowoff[r] + cm);
        float2 z0 = *(const float2*)(zb + rowoff[r] + c0);
        float2 zp = *(const float2*)(zb + rowoff[r] + cp);
        int2   km = *(const int2*)(mb + rowoff[r] + cm);
        int2   k0 = *(const int2*)(mb + rowoff[r] + c0);
        int2   kp = *(const int2*)(mb + rowoff[r] + cp);

        const float xv[6] = {xm.x, xm.y, x0.x, x0.y, xp.x, xp.y};
        const float yv[6] = {ym.x, ym.y, y0.x, y0.y, yp.x, yp.y};
        const float zv[6] = {zm.x, zm.y, z0.x, z0.y, zp.x, zp.y};
        const int   mv[6] = {km.x, km.y, k0.x, k0.y, kp.x, kp.y};

        #pragma unroll
        for (int j = 0; j < 5; ++j) {
            float dx = xv[j] - cx2.x, dy = yv[j] - cy2.x, dz = zv[j] - cz2.x;
            float d2 = dx * dx + dy * dy + dz * dz;
            wa[r][j] = (hv[r] && mv[j]) ? d2 : 1e30f;       // masked -> exp -> 0
            float ex = xv[j + 1] - cx2.y, ey = yv[j + 1] - cy2.y, ez = zv[j + 1] - cz2.y;
            float e2 = ex * ex + ey * ey + ez * ez;
            wb_[r][j] = (hv[r] && mv[j + 1]) ? e2 : 1e30f;
        }
    }
    #pragma unroll
    for (int r = 0; r < 5; ++r)
        #pragma unroll
        for (int j = 0; j < 5; ++j) {
            wa[r][j]  = __expf(-0.5f * wa[r][j]);
            wb_[r][j] = __expf(-0.5f * wb_[r][j]);
        }
    // All weight loads are consumed above -> retired; vmcnt stream is now empty.

    // ---- Per-wave staging tuples: 3 global_load_lds per class ----
    int so0, so1, so2;
    {
        int so[3];
        #pragma unroll
        for (int i = 0; i < 3; ++i) {
            int it = l + 64 * i;
            if (it >= RITEMS) it -= RITEMS;          // pad lanes reload row 0 (never read)
            int r = it / ROWF4;
            int k = it - r * ROWF4;
            so[i] = rowoff[r] + ((W0 - 4 + 4 * k) & (W - 1));
        }
        so0 = so[0]; so1 = so[1]; so2 = so[2];
    }
    char*        ldst = (char*)lds + wv * (4 * SLABF * 4) + l * 16;  // + slab*3072 + i*1024
    const float* wlds = lds + wv * (4 * SLABF);
    const int    lcol = 2 * l + 2;       // local col of leftmost tap in slab row

    // ---- Prime pipeline: classes 0..3 into slabs 0..3 (12 loads in flight) ----
    #pragma unroll
    for (int pc = 0; pc < 4; ++pc) {
        const float* sc = smb + (size_t)pc * HW;
        GLDS16(sc + so0, ldst + pc * 3072);
        GLDS16(sc + so1, ldst + pc * 3072 + 1024);
        GLDS16(sc + so2, ldst + pc * 3072 + 2048);
    }

    float2 acc[C];

    // Per-wave step: counted wait (vmcnt is per-wave -> no barrier needed),
    // compute class CLS from its slab, then refill that slab with class CLS+4.
#define STEP(CLS, KLIT)                                                      \
    do {                                                                     \
        asm volatile("s_waitcnt vmcnt(" #KLIT ")" ::: "memory");             \
        const float* rw = wlds + ((CLS) & 3) * SLABF + lcol;                 \
        float a0 = 0.f, a1 = 0.f;                                            \
        _Pragma("unroll")                                                    \
        for (int r = 0; r < 5; ++r) {                                        \
            const float* p = rw + r * ROWF;                                  \
            float2 u0 = *(const float2*)(p);                                 \
            float2 u1 = *(const float2*)(p + 2);                             \
            float2 u2 = *(const float2*)(p + 4);                             \
            a0 = fmaf(wa[r][0], u0.x, a0);  a0 = fmaf(wa[r][1], u0.y, a0);   \
            a0 = fmaf(wa[r][2], u1.x, a0);  a0 = fmaf(wa[r][3], u1.y, a0);   \
            a0 = fmaf(wa[r][4], u2.x, a0);                                   \
            a1 = fmaf(wb_[r][0], u0.y, a1); a1 = fmaf(wb_[r][1], u1.x, a1);  \
            a1 = fmaf(wb_[r][2], u1.y, a1); a1 = fmaf(wb_[r][3], u2.x, a1);  \
            a1 = fmaf(wb_[r][4], u2.y, a1);                                  \
        }                                                                    \
        acc[CLS].x = a0; acc[CLS].y = a1;                                    \
        __builtin_amdgcn_sched_barrier(0);  /* pin refill after slab reads */\
        if ((CLS) + 4 < C) {                                                 \
            const float* scn = smb + (size_t)((CLS) + 4) * HW;               \
            GLDS16(scn + so0, ldst + ((CLS) & 3) * 3072);                    \
            GLDS16(scn + so1, ldst + ((CLS) & 3) * 3072 + 1024);             \
            GLDS16(scn + so2, ldst + ((CLS) & 3) * 3072 + 2048);             \
        }                                                                    \
    } while (0)

    STEP( 0, 9);  STEP( 1, 9);  STEP( 2, 9);  STEP( 3, 9);
    STEP( 4, 9);  STEP( 5, 9);  STEP( 6, 9);  STEP( 7, 9);
    STEP( 8, 9);  STEP( 9, 9);  STEP(10, 9);  STEP(11, 9);
    STEP(12, 9);  STEP(13, 9);  STEP(14, 9);  STEP(15, 9);
    STEP(16, 9);  STEP(17, 6);  STEP(18, 3);  STEP(19, 0);
#undef STEP

    // ---- Epilogue: coalesced float2 stores ----
    float* ob = out + (size_t)n * C * HW + (size_t)h * W + w;
    #pragma unroll
    for (int c = 0; c < C; ++c)
        *(float2*)(ob + (size_t)c * HW) = acc[c];
}

extern "C" void kernel_launch(void* const* d_in, const int* in_sizes, int n_in,
                              void* d_out, int out_size, void* d_ws, size_t ws_size,
                              hipStream_t stream) {
    const float* xyz     = (const float*)d_in[0];
    const float* softmax = (const float*)d_in[1];
    const int*   mask    = (const int*)d_in[2];
    float*       out     = (float*)d_out;

    const int grid = N * H * (W / TILE);     // 512 blocks
    lcl_xyz_kernel<<<grid, BLK, 0, stream>>>(xyz, softmax, mask, out);
}